// Round 4
// baseline (255.400 us; speedup 1.0000x reference)
//
#include <hip/hip_runtime.h>

// Spiking LayerNorm:
//   x: [T*B, N, D] fp32, T=4, B=64, N=196, D=768
//   chain over t: X += x_t; Y = LN(X)*((t+1)/4); out_t = Y - Y_prev
//
// One 64-lane wave owns one (b,n) chain. X and Y_prev live in registers
// (3 vec4 per lane). Mean/var via shfl-xor butterfly over 64 lanes.
// All 4 timesteps' inputs prefetched up front (independent loads -> MLP).
// Purely memory-bound: 154 MB in + 154 MB out -> ~49 us floor @ 6.3 TB/s.

#define TT 4
#define D 768
#define VPL 3          // vec4 per lane: 768 / 4 / 64 = 3
#define EPS 1e-5f

typedef float f4 __attribute__((ext_vector_type(4)));   // clang vector: ok for nontemporal builtins

__global__ __launch_bounds__(256, 4) void spiking_ln_kernel(
    const float* __restrict__ x,
    const float* __restrict__ weight,
    const float* __restrict__ bias,
    float* __restrict__ out,
    int nrows)                      // B*N = 12544 rows per timestep
{
    const int lane = threadIdx.x & 63;
    const int wav  = threadIdx.x >> 6;
    const int row  = blockIdx.x * 4 + wav;
    if (row >= nrows) return;

    const size_t rowoff  = (size_t)row * D;
    const size_t tstride = (size_t)nrows * D;   // elements per timestep slab

    // ---- prefetch: all 4 timesteps x 3 vec4 (independent, one burst) ----
    f4 xv[TT][VPL];
#pragma unroll
    for (int t = 0; t < TT; ++t) {
        const f4* __restrict__ xin =
            reinterpret_cast<const f4*>(x + (size_t)t * tstride + rowoff);
#pragma unroll
        for (int j = 0; j < VPL; ++j)
            xv[t][j] = __builtin_nontemporal_load(&xin[lane + 64 * j]);
    }

    // weight/bias fragments (reused all 4 timesteps; keep cached)
    f4 w[VPL], bv[VPL];
#pragma unroll
    for (int j = 0; j < VPL; ++j) {
        w[j]  = reinterpret_cast<const f4*>(weight)[lane + 64 * j];
        bv[j] = reinterpret_cast<const f4*>(bias)[lane + 64 * j];
    }

    f4 X[VPL], yprev[VPL];
#pragma unroll
    for (int j = 0; j < VPL; ++j) {
        X[j]     = (f4)0.0f;
        yprev[j] = (f4)0.0f;
    }

#pragma unroll
    for (int t = 0; t < TT; ++t) {
        // X += x_t
#pragma unroll
        for (int j = 0; j < VPL; ++j)
            X[j] += xv[t][j];

        // single-pass sum + sumsq (no cancellation risk: |mu| << sqrt(var))
        float s = 0.f, ss = 0.f;
#pragma unroll
        for (int j = 0; j < VPL; ++j) {
            s  += X[j].x + X[j].y + X[j].z + X[j].w;
            ss += X[j].x * X[j].x + X[j].y * X[j].y
                + X[j].z * X[j].z + X[j].w * X[j].w;
        }
#pragma unroll
        for (int off = 32; off >= 1; off >>= 1) {
            s  += __shfl_xor(s,  off, 64);
            ss += __shfl_xor(ss, off, 64);
        }

        const float mu    = s * (1.0f / D);
        const float var   = ss * (1.0f / D) - mu * mu;
        const float rs    = rsqrtf(var + EPS);
        const float scale = (float)(t + 1) * 0.25f;

        f4* __restrict__ oo =
            reinterpret_cast<f4*>(out + (size_t)t * tstride + rowoff);

#pragma unroll
        for (int j = 0; j < VPL; ++j) {
            f4 y = (X[j] - mu) * rs * w[j] + bv[j];
            y *= scale;
            f4 o = y - yprev[j];
            __builtin_nontemporal_store(o, &oo[lane + 64 * j]);
            yprev[j] = y;
        }
    }
}

extern "C" void kernel_launch(void* const* d_in, const int* in_sizes, int n_in,
                              void* d_out, int out_size, void* d_ws, size_t ws_size,
                              hipStream_t stream)
{
    const float* x      = (const float*)d_in[0];
    const float* weight = (const float*)d_in[1];
    const float* bias   = (const float*)d_in[2];
    float* out          = (float*)d_out;

    const int total = in_sizes[0];            // 256*196*768
    const int nrows = total / (TT * D);       // 12544 chains

    const int waves_per_block = 4;            // 256 threads
    const int grid = (nrows + waves_per_block - 1) / waves_per_block;

    spiking_ln_kernel<<<grid, 256, 0, stream>>>(x, weight, bias, out, nrows);
}

// Round 7
// 254.850 us; speedup vs baseline: 1.0022x; 1.0022x over previous
//
#include <hip/hip_runtime.h>

// Spiking LayerNorm:
//   x: [T*B, N, D] fp32, T=4, B=64, N=196, D=768
//   chain over t: X += x_t; Y = LN(X)*((t+1)/4); out_t = Y - Y_prev
//
// One 64-lane wave owns one (b,n) chain. X and Y_prev live in registers
// (3 vec4 per lane). Mean/var via shfl-xor butterfly over 64 lanes.
// All 4 timesteps' inputs prefetched up front (independent loads -> MLP).
// Purely memory-bound: 154 MB in + 154 MB out -> ~47 us floor @ 6.6 TB/s.
//
// launch_bounds(256,3): 170-VGPR budget. (256,4) would cap at 128 VGPR --
// live state is ~110-125 (xv 48 + w/bv 24 + X/yprev 24 + addrs + temps),
// too close to the spill cliff. 3 waves/SIMD is plenty for a streaming kernel.

#define TT 4
#define D 768
#define VPL 3          // vec4 per lane: 768 / 4 / 64 = 3
#define EPS 1e-5f

typedef float f4 __attribute__((ext_vector_type(4)));   // clang vector: ok for nontemporal builtins

__global__ __launch_bounds__(256, 3) void spiking_ln_kernel(
    const float* __restrict__ x,
    const float* __restrict__ weight,
    const float* __restrict__ bias,
    float* __restrict__ out,
    int nrows)                      // B*N = 12544 rows per timestep
{
    const int lane = threadIdx.x & 63;
    const int wav  = threadIdx.x >> 6;
    const int row  = blockIdx.x * 4 + wav;
    if (row >= nrows) return;

    const size_t rowoff  = (size_t)row * D;
    const size_t tstride = (size_t)nrows * D;   // elements per timestep slab

    // ---- prefetch: all 4 timesteps x 3 vec4 (independent, one burst) ----
    f4 xv[TT][VPL];
#pragma unroll
    for (int t = 0; t < TT; ++t) {
        const f4* __restrict__ xin =
            reinterpret_cast<const f4*>(x + (size_t)t * tstride + rowoff);
#pragma unroll
        for (int j = 0; j < VPL; ++j)
            xv[t][j] = __builtin_nontemporal_load(&xin[lane + 64 * j]);
    }

    // weight/bias fragments (reused all 4 timesteps; keep cached)
    f4 w[VPL], bv[VPL];
#pragma unroll
    for (int j = 0; j < VPL; ++j) {
        w[j]  = reinterpret_cast<const f4*>(weight)[lane + 64 * j];
        bv[j] = reinterpret_cast<const f4*>(bias)[lane + 64 * j];
    }

    f4 X[VPL], yprev[VPL];
#pragma unroll
    for (int j = 0; j < VPL; ++j) {
        X[j]     = (f4)0.0f;
        yprev[j] = (f4)0.0f;
    }

#pragma unroll
    for (int t = 0; t < TT; ++t) {
        // X += x_t
#pragma unroll
        for (int j = 0; j < VPL; ++j)
            X[j] += xv[t][j];

        // single-pass sum + sumsq (no cancellation risk: |mu| << sqrt(var))
        float s = 0.f, ss = 0.f;
#pragma unroll
        for (int j = 0; j < VPL; ++j) {
            s  += X[j].x + X[j].y + X[j].z + X[j].w;
            ss += X[j].x * X[j].x + X[j].y * X[j].y
                + X[j].z * X[j].z + X[j].w * X[j].w;
        }
#pragma unroll
        for (int off = 32; off >= 1; off >>= 1) {
            s  += __shfl_xor(s,  off, 64);
            ss += __shfl_xor(ss, off, 64);
        }

        const float mu    = s * (1.0f / D);
        const float var   = ss * (1.0f / D) - mu * mu;
        const float rs    = rsqrtf(var + EPS);
        const float scale = (float)(t + 1) * 0.25f;

        f4* __restrict__ oo =
            reinterpret_cast<f4*>(out + (size_t)t * tstride + rowoff);

#pragma unroll
        for (int j = 0; j < VPL; ++j) {
            f4 y = (X[j] - mu) * rs * w[j] + bv[j];
            y *= scale;
            f4 o = y - yprev[j];
            __builtin_nontemporal_store(o, &oo[lane + 64 * j]);
            yprev[j] = y;
        }
    }
}

extern "C" void kernel_launch(void* const* d_in, const int* in_sizes, int n_in,
                              void* d_out, int out_size, void* d_ws, size_t ws_size,
                              hipStream_t stream)
{
    const float* x      = (const float*)d_in[0];
    const float* weight = (const float*)d_in[1];
    const float* bias   = (const float*)d_in[2];
    float* out          = (float*)d_out;

    const int total = in_sizes[0];            // 256*196*768
    const int nrows = total / (TT * D);       // 12544 chains

    const int waves_per_block = 4;            // 256 threads
    const int grid = (nrows + waves_per_block - 1) / waves_per_block;

    spiking_ln_kernel<<<grid, 256, 0, stream>>>(x, weight, bias, out, nrows);
}